// Round 1
// baseline (432.099 us; speedup 1.0000x reference)
//
#include <hip/hip_runtime.h>

constexpr int NN = 100000;   // nodes
constexpr int NE = 1600000;  // edges
constexpr int F  = 64;       // F_IN == F_OUT

// ---------------------------------------------------------------------------
// K1: CSR row_ptr from sorted COO rows via per-row lower_bound binary search.
// ---------------------------------------------------------------------------
__global__ __launch_bounds__(256)
void build_row_ptr_k(const int* __restrict__ rows, int* __restrict__ row_ptr) {
    int r = blockIdx.x * 256 + threadIdx.x;
    if (r > NN) return;
    int lo = 0, hi = NE;
    while (lo < hi) {
        int mid = (lo + hi) >> 1;
        if (rows[mid] < r) lo = mid + 1; else hi = mid;
    }
    row_ptr[r] = lo;  // first edge with rows[e] >= r; row_ptr[NN] == NE
}

// ---------------------------------------------------------------------------
// K2/K3: SpMM, one wave per row, lane = feature. cols[e]/vals[e] are
// wave-uniform (scalar loads); x-gather is one coalesced 256B read per edge.
// SECOND: dst = 2*A@src - x0   (Chebyshev recurrence fused into epilogue)
// ---------------------------------------------------------------------------
template<bool SECOND>
__global__ __launch_bounds__(256)
void spmm_k(const int* __restrict__ row_ptr, const int* __restrict__ cols,
            const float* __restrict__ vals, const float* __restrict__ src,
            const float* __restrict__ x0, float* __restrict__ dst) {
    const int lane = threadIdx.x & 63;
    const int i = blockIdx.x * 4 + (threadIdx.x >> 6);
    if (i >= NN) return;
    const int e0 = row_ptr[i];
    const int e1 = row_ptr[i + 1];
    float acc = 0.f;
    for (int e = e0; e < e1; ++e) {
        acc += vals[e] * src[(size_t)cols[e] * F + lane];
    }
    float r = SECOND ? (2.f * acc - x0[(size_t)i * F + lane]) : acc;
    dst[(size_t)i * F + lane] = r;
}

// ---------------------------------------------------------------------------
// K4: out[i,:] = x[i,:]@W0 + t1[i,:]@W1 + t2[i,:]@W2 + bias
// Viewed as [N x 192] @ [192 x 64]. All weights (48KB) staged in LDS once per
// block. 64-row tile, 256 threads, 4x4 fp32 accumulators per thread.
// ---------------------------------------------------------------------------
__global__ __launch_bounds__(256)
void dense_k(const float* __restrict__ x, const float* __restrict__ t1,
             const float* __restrict__ t2, const float* __restrict__ w,
             const float* __restrict__ bias, float* __restrict__ out) {
    __shared__ float Wc[192 * 64];  // 48 KB: concat(W0,W1,W2) row-major [k][f]
    __shared__ float As[16 * 64];   // 4 KB: A-chunk transposed [k'][row]
    const int tid = threadIdx.x;

    {   // cooperative weight load: 12288 floats = 3072 float4
        const float4* srcw = (const float4*)w;
        float4* dstw = (float4*)Wc;
        #pragma unroll
        for (int idx = 0; idx < 12; ++idx)
            dstw[tid + idx * 256] = srcw[tid + idx * 256];
    }

    const int row0 = blockIdx.x * 64;
    const int tx = tid & 15;   // col group: cols tx*4 .. tx*4+3
    const int ty = tid >> 4;   // row group: rows ty*4 .. ty*4+3
    float acc[4][4] = {};

    const int srow   = tid >> 2;        // staging: row in tile
    const int skp    = (tid & 3) * 4;   // staging: k' base
    const int grow_s = row0 + srow;

    __syncthreads();

    for (int chunk = 0; chunk < 12; ++chunk) {
        const float* src = (chunk < 4) ? x : (chunk < 8) ? t1 : t2;
        const int kbase = (chunk & 3) * 16;

        float4 v = make_float4(0.f, 0.f, 0.f, 0.f);
        if (grow_s < NN)
            v = *(const float4*)(src + (size_t)grow_s * F + kbase + skp);
        __syncthreads();  // previous chunk's As reads done before overwrite
        As[(skp + 0) * 64 + srow] = v.x;
        As[(skp + 1) * 64 + srow] = v.y;
        As[(skp + 2) * 64 + srow] = v.z;
        As[(skp + 3) * 64 + srow] = v.w;
        __syncthreads();

        const int wbase = chunk * 16 * 64;  // (chunk>>2)*64*64 + kbase*64
        #pragma unroll
        for (int kp = 0; kp < 16; ++kp) {
            float4 a = *(const float4*)(As + kp * 64 + ty * 4);
            float4 b = *(const float4*)(Wc + wbase + kp * 64 + tx * 4);
            acc[0][0] += a.x * b.x; acc[0][1] += a.x * b.y; acc[0][2] += a.x * b.z; acc[0][3] += a.x * b.w;
            acc[1][0] += a.y * b.x; acc[1][1] += a.y * b.y; acc[1][2] += a.y * b.z; acc[1][3] += a.y * b.w;
            acc[2][0] += a.z * b.x; acc[2][1] += a.z * b.y; acc[2][2] += a.z * b.z; acc[2][3] += a.z * b.w;
            acc[3][0] += a.w * b.x; acc[3][1] += a.w * b.y; acc[3][2] += a.w * b.z; acc[3][3] += a.w * b.w;
        }
    }

    float4 bv = *(const float4*)(bias + tx * 4);
    #pragma unroll
    for (int r = 0; r < 4; ++r) {
        int grow = row0 + ty * 4 + r;
        if (grow < NN) {
            float4 o;
            o.x = acc[r][0] + bv.x;
            o.y = acc[r][1] + bv.y;
            o.z = acc[r][2] + bv.z;
            o.w = acc[r][3] + bv.w;
            *(float4*)(out + (size_t)grow * F + tx * 4) = o;
        }
    }
}

extern "C" void kernel_launch(void* const* d_in, const int* in_sizes, int n_in,
                              void* d_out, int out_size, void* d_ws, size_t ws_size,
                              hipStream_t stream) {
    const float* x    = (const float*)d_in[0];
    const int*   rows = (const int*)  d_in[1];
    const int*   cols = (const int*)  d_in[2];
    const float* vals = (const float*)d_in[3];
    const float* w    = (const float*)d_in[4];  // [3][64][64]
    const float* bias = (const float*)d_in[5];  // [64]
    float* out = (float*)d_out;

    // Workspace layout (all fully rewritten every call; safe vs 0xAA poison):
    //   [0, 400004)            row_ptr  (NN+1 ints)
    //   [400128, +25.6MB)      t1 = A@x
    //   [.. , +25.6MB)         t2 = 2*A@t1 - x          total ~51.6 MB
    char* ws = (char*)d_ws;
    int* row_ptr = (int*)ws;
    size_t off = (((size_t)(NN + 1) * sizeof(int)) + 255) & ~(size_t)255;
    float* t1 = (float*)(ws + off);
    float* t2 = t1 + (size_t)NN * F;

    build_row_ptr_k<<<(NN + 1 + 255) / 256, 256, 0, stream>>>(rows, row_ptr);
    spmm_k<false><<<NN / 4, 256, 0, stream>>>(row_ptr, cols, vals, x,  nullptr, t1);
    spmm_k<true ><<<NN / 4, 256, 0, stream>>>(row_ptr, cols, vals, t1, x,       t2);
    dense_k<<<(NN + 63) / 64, 256, 0, stream>>>(x, t1, t2, w, bias, out);
}

// Round 2
// 345.429 us; speedup vs baseline: 1.2509x; 1.2509x over previous
//
#include <hip/hip_runtime.h>

constexpr int NN = 100000;   // nodes
constexpr int NE = 1600000;  // edges
constexpr int F  = 64;       // F_IN == F_OUT

// ---------------------------------------------------------------------------
// K1: CSR row_ptr from sorted COO rows via per-row lower_bound binary search.
// ---------------------------------------------------------------------------
__global__ __launch_bounds__(256)
void build_row_ptr_k(const int* __restrict__ rows, int* __restrict__ row_ptr) {
    int r = blockIdx.x * 256 + threadIdx.x;
    if (r > NN) return;
    int lo = 0, hi = NE;
    while (lo < hi) {
        int mid = (lo + hi) >> 1;
        if (rows[mid] < r) lo = mid + 1; else hi = mid;
    }
    row_ptr[r] = lo;  // first edge with rows[e] >= r; row_ptr[NN] == NE
}

// ---------------------------------------------------------------------------
// K2/K3: SpMM, one wave per row, lane = feature.
// Edge metadata (cols/vals) is prefetched COALESCED into registers (lane l
// holds edge e0+l), then broadcast per-edge via __shfl. This makes the row
// gathers address-independent across the unrolled inner loop so the compiler
// can keep many 256B loads in flight (vmcnt pipelining) instead of the old
// serial cols[e] -> address -> load chain (~60 cyc/edge measured).
// SECOND: dst = 2*A@src - x0   (Chebyshev recurrence fused into epilogue)
// ---------------------------------------------------------------------------
template<bool SECOND>
__global__ __launch_bounds__(256)
void spmm_k(const int* __restrict__ row_ptr, const int* __restrict__ cols,
            const float* __restrict__ vals, const float* __restrict__ src,
            const float* __restrict__ x0, float* __restrict__ dst) {
    const int lane = threadIdx.x & 63;
    const int i = blockIdx.x * 4 + (threadIdx.x >> 6);
    if (i >= NN) return;
    const int e0 = row_ptr[i];
    const int e1 = row_ptr[i + 1];
    float acc = 0.f;
    for (int base = e0; base < e1; base += 64) {
        const int n = min(64, e1 - base);
        int   c = 0;
        float v = 0.f;
        if (lane < n) {           // coalesced metadata prefetch
            c = cols[base + lane];
            v = vals[base + lane];
        }
        #pragma unroll 8
        for (int j = 0; j < n; ++j) {
            int   cj = __shfl(c, j);
            float vj = __shfl(v, j);
            acc += vj * src[(size_t)cj * F + lane];
        }
    }
    float r = SECOND ? (2.f * acc - x0[(size_t)i * F + lane]) : acc;
    dst[(size_t)i * F + lane] = r;
}

// ---------------------------------------------------------------------------
// K4: out[i,:] = x[i,:]@W0 + t1[i,:]@W1 + t2[i,:]@W2 + bias
// Viewed as [N x 192] @ [192 x 64]. All weights (48KB) staged in LDS once per
// block. 64-row tile, 256 threads, 4x4 fp32 accumulators per thread.
// ---------------------------------------------------------------------------
__global__ __launch_bounds__(256)
void dense_k(const float* __restrict__ x, const float* __restrict__ t1,
             const float* __restrict__ t2, const float* __restrict__ w,
             const float* __restrict__ bias, float* __restrict__ out) {
    __shared__ float Wc[192 * 64];  // 48 KB: concat(W0,W1,W2) row-major [k][f]
    __shared__ float As[16 * 64];   // 4 KB: A-chunk transposed [k'][row]
    const int tid = threadIdx.x;

    {   // cooperative weight load: 12288 floats = 3072 float4
        const float4* srcw = (const float4*)w;
        float4* dstw = (float4*)Wc;
        #pragma unroll
        for (int idx = 0; idx < 12; ++idx)
            dstw[tid + idx * 256] = srcw[tid + idx * 256];
    }

    const int row0 = blockIdx.x * 64;
    const int tx = tid & 15;   // col group: cols tx*4 .. tx*4+3
    const int ty = tid >> 4;   // row group: rows ty*4 .. ty*4+3
    float acc[4][4] = {};

    const int srow   = tid >> 2;        // staging: row in tile
    const int skp    = (tid & 3) * 4;   // staging: k' base
    const int grow_s = row0 + srow;

    __syncthreads();

    for (int chunk = 0; chunk < 12; ++chunk) {
        const float* src = (chunk < 4) ? x : (chunk < 8) ? t1 : t2;
        const int kbase = (chunk & 3) * 16;

        float4 v = make_float4(0.f, 0.f, 0.f, 0.f);
        if (grow_s < NN)
            v = *(const float4*)(src + (size_t)grow_s * F + kbase + skp);
        __syncthreads();  // previous chunk's As reads done before overwrite
        As[(skp + 0) * 64 + srow] = v.x;
        As[(skp + 1) * 64 + srow] = v.y;
        As[(skp + 2) * 64 + srow] = v.z;
        As[(skp + 3) * 64 + srow] = v.w;
        __syncthreads();

        const int wbase = chunk * 16 * 64;  // (chunk>>2)*64*64 + kbase*64
        #pragma unroll
        for (int kp = 0; kp < 16; ++kp) {
            float4 a = *(const float4*)(As + kp * 64 + ty * 4);
            float4 b = *(const float4*)(Wc + wbase + kp * 64 + tx * 4);
            acc[0][0] += a.x * b.x; acc[0][1] += a.x * b.y; acc[0][2] += a.x * b.z; acc[0][3] += a.x * b.w;
            acc[1][0] += a.y * b.x; acc[1][1] += a.y * b.y; acc[1][2] += a.y * b.z; acc[1][3] += a.y * b.w;
            acc[2][0] += a.z * b.x; acc[2][1] += a.z * b.y; acc[2][2] += a.z * b.z; acc[2][3] += a.z * b.w;
            acc[3][0] += a.w * b.x; acc[3][1] += a.w * b.y; acc[3][2] += a.w * b.z; acc[3][3] += a.w * b.w;
        }
    }

    float4 bv = *(const float4*)(bias + tx * 4);
    #pragma unroll
    for (int r = 0; r < 4; ++r) {
        int grow = row0 + ty * 4 + r;
        if (grow < NN) {
            float4 o;
            o.x = acc[r][0] + bv.x;
            o.y = acc[r][1] + bv.y;
            o.z = acc[r][2] + bv.z;
            o.w = acc[r][3] + bv.w;
            *(float4*)(out + (size_t)grow * F + tx * 4) = o;
        }
    }
}

extern "C" void kernel_launch(void* const* d_in, const int* in_sizes, int n_in,
                              void* d_out, int out_size, void* d_ws, size_t ws_size,
                              hipStream_t stream) {
    const float* x    = (const float*)d_in[0];
    const int*   rows = (const int*)  d_in[1];
    const int*   cols = (const int*)  d_in[2];
    const float* vals = (const float*)d_in[3];
    const float* w    = (const float*)d_in[4];  // [3][64][64]
    const float* bias = (const float*)d_in[5];  // [64]
    float* out = (float*)d_out;

    // Workspace layout (all fully rewritten every call; safe vs 0xAA poison):
    //   [0, 400004)            row_ptr  (NN+1 ints)
    //   [400128, +25.6MB)      t1 = A@x
    //   [.. , +25.6MB)         t2 = 2*A@t1 - x          total ~51.6 MB
    char* ws = (char*)d_ws;
    int* row_ptr = (int*)ws;
    size_t off = (((size_t)(NN + 1) * sizeof(int)) + 255) & ~(size_t)255;
    float* t1 = (float*)(ws + off);
    float* t2 = t1 + (size_t)NN * F;

    build_row_ptr_k<<<(NN + 1 + 255) / 256, 256, 0, stream>>>(rows, row_ptr);
    spmm_k<false><<<NN / 4, 256, 0, stream>>>(row_ptr, cols, vals, x,  nullptr, t1);
    spmm_k<true ><<<NN / 4, 256, 0, stream>>>(row_ptr, cols, vals, t1, x,       t2);
    dense_k<<<(NN + 63) / 64, 256, 0, stream>>>(x, t1, t2, w, bias, out);
}

// Round 4
// 213.553 us; speedup vs baseline: 2.0234x; 1.6175x over previous
//
#include <hip/hip_runtime.h>

constexpr int NN = 100000;   // nodes
constexpr int NE = 1600000;  // edges
constexpr int F  = 64;       // F_IN == F_OUT

typedef short bf16x8 __attribute__((ext_vector_type(8)));
typedef float f32x4  __attribute__((ext_vector_type(4)));

// bf16 helpers: bf16 bits<<16 == fp32 bit pattern.
__device__ __forceinline__ float bf_lo(unsigned u) { return __uint_as_float(u << 16); }
__device__ __forceinline__ float bf_hi(unsigned u) { return __uint_as_float(u & 0xFFFF0000u); }
__device__ __forceinline__ unsigned pack_bf16(float a, float b) {  // RNE
    unsigned ua = __float_as_uint(a);
    unsigned ub = __float_as_uint(b);
    ua = (ua + 0x7FFFu + ((ua >> 16) & 1u)) >> 16;
    ub = (ub + 0x7FFFu + ((ub >> 16) & 1u)) & 0xFFFF0000u;
    return ua | ub;
}

// ---------------------------------------------------------------------------
// K1: CSR row_ptr from sorted COO rows via per-row lower_bound binary search.
// ---------------------------------------------------------------------------
__global__ __launch_bounds__(256)
void build_row_ptr_k(const int* __restrict__ rows, int* __restrict__ row_ptr) {
    int r = blockIdx.x * 256 + threadIdx.x;
    if (r > NN) return;
    int lo = 0, hi = NE;
    while (lo < hi) {
        int mid = (lo + hi) >> 1;
        if (rows[mid] < r) lo = mid + 1; else hi = mid;
    }
    row_ptr[r] = lo;
}

// ---------------------------------------------------------------------------
// K2: x (fp32) -> x_bf (bf16), 8 elems/thread.
// ---------------------------------------------------------------------------
__global__ __launch_bounds__(256)
void cvt_x_k(const float* __restrict__ x, ushort* __restrict__ xb) {
    int tid = blockIdx.x * 256 + threadIdx.x;
    if (tid >= NN * F / 8) return;
    const float4* p = (const float4*)x + (size_t)tid * 2;
    float4 a = p[0], b = p[1];
    uint4 o = make_uint4(pack_bf16(a.x, a.y), pack_bf16(a.z, a.w),
                         pack_bf16(b.x, b.y), pack_bf16(b.z, b.w));
    ((uint4*)xb)[tid] = o;
}

// ---------------------------------------------------------------------------
// K3: W [192][64] fp32 -> Wt [64][192] bf16 (transposed so B-fragments are
// one contiguous 16B load: Wt[n][kbase + quad*8 + j]).
// ---------------------------------------------------------------------------
__global__ __launch_bounds__(256)
void cvt_w_k(const float* __restrict__ w, ushort* __restrict__ wt) {
    int tid = blockIdx.x * 256 + threadIdx.x;
    if (tid >= 192 * 64) return;
    int k = tid >> 6, n = tid & 63;
    unsigned u = __float_as_uint(w[tid]);
    u = (u + 0x7FFFu + ((u >> 16) & 1u)) >> 16;
    wt[n * 192 + k] = (ushort)u;
}

// ---------------------------------------------------------------------------
// K4/K5: bf16 SpMM, one wave per row. 8 edges processed concurrently:
// egrp = lane>>3 picks the edge, fgrp = lane&7 picks 8 features (one 16B
// dwordx4 per lane -> full row of 8 edges per wave step, 1KB/instr).
// Metadata prefetched coalesced (lane l holds edge base+l), broadcast via
// shfl. fp32 accumulate; xor-butterfly reduce over egrp; lanes 0-7 store
// the packed bf16 row. SECOND: dst = 2*A@src - x0 (Chebyshev fused).
// ---------------------------------------------------------------------------
template<bool SECOND>
__global__ __launch_bounds__(256)
void spmm_k(const int* __restrict__ row_ptr, const int* __restrict__ cols,
            const float* __restrict__ vals, const ushort* __restrict__ src,
            const ushort* __restrict__ x0, ushort* __restrict__ dst) {
    const int lane = threadIdx.x & 63;
    const int i = blockIdx.x * 4 + (threadIdx.x >> 6);
    if (i >= NN) return;
    const int e0 = row_ptr[i];
    const int e1 = row_ptr[i + 1];
    const int fgrp = lane & 7;
    const int egrp = lane >> 3;
    float acc[8] = {};
    for (int base = e0; base < e1; base += 64) {
        const int n = min(64, e1 - base);
        int c = 0; float v = 0.f;
        if (lane < n) {               // coalesced metadata prefetch
            c = cols[base + lane];
            v = vals[base + lane];
        }
        const int steps = (n + 7) >> 3;
        #pragma unroll 4
        for (int s = 0; s < steps; ++s) {
            int   cj = __shfl(c, s * 8 + egrp);
            float vj = __shfl(v, s * 8 + egrp);   // 0 for padded slots
            uint4 raw = *(const uint4*)(src + (size_t)cj * F + fgrp * 8);
            acc[0] += vj * bf_lo(raw.x); acc[1] += vj * bf_hi(raw.x);
            acc[2] += vj * bf_lo(raw.y); acc[3] += vj * bf_hi(raw.y);
            acc[4] += vj * bf_lo(raw.z); acc[5] += vj * bf_hi(raw.z);
            acc[6] += vj * bf_lo(raw.w); acc[7] += vj * bf_hi(raw.w);
        }
    }
    #pragma unroll
    for (int m = 8; m < 64; m <<= 1)
        #pragma unroll
        for (int t = 0; t < 8; ++t)
            acc[t] += __shfl_xor(acc[t], m);
    if (egrp == 0) {                  // lanes 0-7 write the 128B row
        float r[8];
        if (SECOND) {
            uint4 xr = *(const uint4*)(x0 + (size_t)i * F + fgrp * 8);
            r[0] = 2.f * acc[0] - bf_lo(xr.x); r[1] = 2.f * acc[1] - bf_hi(xr.x);
            r[2] = 2.f * acc[2] - bf_lo(xr.y); r[3] = 2.f * acc[3] - bf_hi(xr.y);
            r[4] = 2.f * acc[4] - bf_lo(xr.z); r[5] = 2.f * acc[5] - bf_hi(xr.z);
            r[6] = 2.f * acc[6] - bf_lo(xr.w); r[7] = 2.f * acc[7] - bf_hi(xr.w);
        } else {
            #pragma unroll
            for (int t = 0; t < 8; ++t) r[t] = acc[t];
        }
        uint4 o = make_uint4(pack_bf16(r[0], r[1]), pack_bf16(r[2], r[3]),
                             pack_bf16(r[4], r[5]), pack_bf16(r[6], r[7]));
        *(uint4*)(dst + (size_t)i * F + fgrp * 8) = o;
    }
}

// ---------------------------------------------------------------------------
// K6: dense epilogue via bf16 MFMA, zero LDS, zero barriers.
// out[100000x64] = [x|t1|t2](bf16, Nx192) @ Wt^T + bias, fp32 out.
// Block = 64 rows x 64 cols; wave w takes rows [row0+16w, +16), all 64 cols
// (4 col-tiles). Per kbase (6 x K=32): A-frag = one 16B load
// (A[m=lane&15][k=quad*8+j]); B-frag = one 16B load from Wt[n][k...].
// C/D layout: col=lane&15, row=quad*4+reg (m89-verified).
// ---------------------------------------------------------------------------
__global__ __launch_bounds__(256)
void dense_k(const ushort* __restrict__ xb, const ushort* __restrict__ t1,
             const ushort* __restrict__ t2, const ushort* __restrict__ wt,
             const float* __restrict__ bias, float* __restrict__ out) {
    const int tid  = threadIdx.x;
    const int lane = tid & 63;
    const int wv   = tid >> 6;
    const int row0 = blockIdx.x * 64 + wv * 16;
    const int m    = lane & 15;
    const int quad = lane >> 4;
    int arow = row0 + m;
    if (arow >= NN) arow = NN - 1;          // clamp; stores are guarded

    f32x4 acc[4] = {};
    #pragma unroll
    for (int kb = 0; kb < 6; ++kb) {
        const int kbase = kb * 32;
        const ushort* seg = (kb < 2) ? xb : (kb < 4) ? t1 : t2;
        const int off = (kbase & 63) + quad * 8;
        bf16x8 a = *(const bf16x8*)(seg + (size_t)arow * F + off);
        #pragma unroll
        for (int t = 0; t < 4; ++t) {
            const int n = t * 16 + m;
            bf16x8 b = *(const bf16x8*)(wt + (size_t)n * 192 + kbase + quad * 8);
            acc[t] = __builtin_amdgcn_mfma_f32_16x16x32_bf16(a, b, acc[t], 0, 0, 0);
        }
    }
    #pragma unroll
    for (int t = 0; t < 4; ++t) {
        const int col = t * 16 + m;
        const float bv = bias[col];
        #pragma unroll
        for (int r = 0; r < 4; ++r) {
            const int grow = row0 + quad * 4 + r;
            if (grow < NN) out[(size_t)grow * F + col] = acc[t][r] + bv;
        }
    }
}

extern "C" void kernel_launch(void* const* d_in, const int* in_sizes, int n_in,
                              void* d_out, int out_size, void* d_ws, size_t ws_size,
                              hipStream_t stream) {
    const float* x    = (const float*)d_in[0];
    const int*   rows = (const int*)  d_in[1];
    const int*   cols = (const int*)  d_in[2];
    const float* vals = (const float*)d_in[3];
    const float* w    = (const float*)d_in[4];  // [3][64][64] == [192][64]
    const float* bias = (const float*)d_in[5];  // [64]
    float* out = (float*)d_out;

    // Workspace (all fully rewritten every call; safe vs 0xAA poison):
    //   row_ptr (NN+1 int) | xb, t1b, t2b (N*64 bf16 each, 12.8MB) | wt (24KB)
    char* ws = (char*)d_ws;
    int* row_ptr = (int*)ws;
    size_t off = (((size_t)(NN + 1) * sizeof(int)) + 255) & ~(size_t)255;
    ushort* xb  = (ushort*)(ws + off);
    ushort* t1b = xb  + (size_t)NN * F;
    ushort* t2b = t1b + (size_t)NN * F;
    ushort* wt  = t2b + (size_t)NN * F;

    build_row_ptr_k<<<(NN + 1 + 255) / 256, 256, 0, stream>>>(rows, row_ptr);
    cvt_x_k<<<(NN * F / 8 + 255) / 256, 256, 0, stream>>>(x, xb);
    cvt_w_k<<<(192 * 64 + 255) / 256, 256, 0, stream>>>(w, wt);
    spmm_k<false><<<NN / 4, 256, 0, stream>>>(row_ptr, cols, vals, xb,  nullptr, t1b);
    spmm_k<true ><<<NN / 4, 256, 0, stream>>>(row_ptr, cols, vals, t1b, xb,      t2b);
    dense_k<<<(NN + 63) / 64, 256, 0, stream>>>(xb, t1b, t2b, wt, bias, out);
}

// Round 5
// 186.057 us; speedup vs baseline: 2.3224x; 1.1478x over previous
//
#include <hip/hip_runtime.h>

constexpr int NN = 100000;   // nodes
constexpr int NE = 1600000;  // edges
constexpr int F  = 64;       // F_IN == F_OUT

typedef short bf16x8 __attribute__((ext_vector_type(8)));
typedef float f32x4  __attribute__((ext_vector_type(4)));

// bf16 helpers: bf16 bits<<16 == fp32 bit pattern.
__device__ __forceinline__ float bf_lo(unsigned u) { return __uint_as_float(u << 16); }
__device__ __forceinline__ float bf_hi(unsigned u) { return __uint_as_float(u & 0xFFFF0000u); }
__device__ __forceinline__ unsigned pack_bf16(float a, float b) {  // RNE
    unsigned ua = __float_as_uint(a);
    unsigned ub = __float_as_uint(b);
    ua = (ua + 0x7FFFu + ((ua >> 16) & 1u)) >> 16;
    ub = (ub + 0x7FFFu + ((ub >> 16) & 1u)) & 0xFFFF0000u;
    return ua | ub;
}

// ---------------------------------------------------------------------------
// K1 prep: ONE dispatch, partitioned by blockIdx:
//   blocks [0,3125):      x fp32 -> bf16, 8 elems/thread (3125*256*8 = NN*F)
//   blocks [3125,9375):   row_ptr via edge-boundary scatter (thread per edge;
//                         rows sorted, so only boundary edges write)
//   blocks [9375,9423):   W [192][64] fp32 -> Wt [64][192] bf16 (transposed)
// ---------------------------------------------------------------------------
constexpr int B_CVT = NN * F / 8 / 256;        // 3125
constexpr int B_RP  = NE / 256;                // 6250
constexpr int B_W   = 192 * 64 / 256;          // 48

__global__ __launch_bounds__(256)
void prep_k(const float* __restrict__ x, ushort* __restrict__ xb,
            const int* __restrict__ rows, int* __restrict__ row_ptr,
            const float* __restrict__ w, ushort* __restrict__ wt) {
    const int b = blockIdx.x;
    if (b < B_CVT) {
        int tid = b * 256 + threadIdx.x;
        const float4* p = (const float4*)x + (size_t)tid * 2;
        float4 a = p[0], c = p[1];
        uint4 o = make_uint4(pack_bf16(a.x, a.y), pack_bf16(a.z, a.w),
                             pack_bf16(c.x, c.y), pack_bf16(c.z, c.w));
        ((uint4*)xb)[tid] = o;
    } else if (b < B_CVT + B_RP) {
        int e = (b - B_CVT) * 256 + threadIdx.x;
        int r1 = rows[e];
        int r2 = (e == NE - 1) ? NN : rows[e + 1];
        for (int r = r1 + 1; r <= r2; ++r) row_ptr[r] = e + 1;
        if (e == 0)
            for (int r = 0; r <= r1; ++r) row_ptr[r] = 0;
    } else {
        int tid = (b - B_CVT - B_RP) * 256 + threadIdx.x;
        int k = tid >> 6, n = tid & 63;
        unsigned u = __float_as_uint(w[tid]);
        u = (u + 0x7FFFu + ((u >> 16) & 1u)) >> 16;
        wt[n * 192 + k] = (ushort)u;
    }
}

// ---------------------------------------------------------------------------
// K2/K3: reduction-free bf16 SpMM. 8 rows per wave: egrp = lane>>3 OWNS row
// rbase+egrp (accumulates only that row), fgrp = lane&7 covers features
// [8*fgrp, +8) via one 16B load. No shfl, no butterfly, no DS traffic (the
// old per-row butterfly was ~24 ds-ops/row on the single LDS pipe — the
// measured bottleneck). Loop runs to the wave-max degree; inactive egrps
// clamp to their last edge (re-reads an L1-resident line, no extra bytes).
// Store: full wave writes 8 consecutive rows = 1KB contiguous.
// SECOND: dst = 2*A@src - x0 (Chebyshev fused).
// ---------------------------------------------------------------------------
template<bool SECOND>
__global__ __launch_bounds__(256)
void spmm_k(const int* __restrict__ row_ptr, const int* __restrict__ cols,
            const float* __restrict__ vals, const ushort* __restrict__ src,
            const ushort* __restrict__ x0, ushort* __restrict__ dst) {
    const int lane = threadIdx.x & 63;
    const int fgrp = lane & 7;
    const int g    = lane >> 3;                       // row within group
    const int r    = (blockIdx.x * 4 + (threadIdx.x >> 6)) * 8 + g;  // < NN (3125*32)
    const int e0 = row_ptr[r];
    const int e1 = row_ptr[r + 1];
    const int deg = e1 - e0;
    int maxdeg = deg;                                  // wave-max over the 8 rows
    maxdeg = max(maxdeg, __shfl_xor(maxdeg, 8));
    maxdeg = max(maxdeg, __shfl_xor(maxdeg, 16));
    maxdeg = max(maxdeg, __shfl_xor(maxdeg, 32));

    float acc[8] = {};
    #pragma unroll 2
    for (int s = 0; s < maxdeg; ++s) {
        const bool act = s < deg;
        int ec = act ? (e0 + s) : (e1 - 1);
        ec = ec < 0 ? 0 : ec;                          // only if a leading row is empty
        const int   cj = cols[ec];
        const float vv = vals[ec];
        const float vj = act ? vv : 0.f;
        uint4 raw = *(const uint4*)(src + (size_t)cj * F + fgrp * 8);
        acc[0] += vj * bf_lo(raw.x); acc[1] += vj * bf_hi(raw.x);
        acc[2] += vj * bf_lo(raw.y); acc[3] += vj * bf_hi(raw.y);
        acc[4] += vj * bf_lo(raw.z); acc[5] += vj * bf_hi(raw.z);
        acc[6] += vj * bf_lo(raw.w); acc[7] += vj * bf_hi(raw.w);
    }

    float o[8];
    if (SECOND) {
        uint4 xr = *(const uint4*)(x0 + (size_t)r * F + fgrp * 8);
        o[0] = 2.f * acc[0] - bf_lo(xr.x); o[1] = 2.f * acc[1] - bf_hi(xr.x);
        o[2] = 2.f * acc[2] - bf_lo(xr.y); o[3] = 2.f * acc[3] - bf_hi(xr.y);
        o[4] = 2.f * acc[4] - bf_lo(xr.z); o[5] = 2.f * acc[5] - bf_hi(xr.z);
        o[6] = 2.f * acc[6] - bf_lo(xr.w); o[7] = 2.f * acc[7] - bf_hi(xr.w);
    } else {
        #pragma unroll
        for (int t = 0; t < 8; ++t) o[t] = acc[t];
    }
    uint4 ov = make_uint4(pack_bf16(o[0], o[1]), pack_bf16(o[2], o[3]),
                          pack_bf16(o[4], o[5]), pack_bf16(o[6], o[7]));
    *(uint4*)(dst + (size_t)r * F + fgrp * 8) = ov;
}

// ---------------------------------------------------------------------------
// K4: dense epilogue via bf16 MFMA, LDS-transposed coalesced stores.
// out[100000x64] = [x|t1|t2](bf16, Nx192) @ Wt^T + bias, fp32 out.
// Wave w: rows [blk*64 + 16w, +16), all 64 cols. A-frag/B-frag = one 16B
// load each (A[m=lane&15][k=quad*8+j]; Wt[n][k] row-contig). C/D layout:
// col=lane&15, row=quad*4+reg. Epilogue: scatter acc(+bias) into a per-wave
// LDS slab (stride 68 floats: 16B-aligned rows, <=2-way banks = free), then
// 4 full-row float4 coalesced stores (was: 16 dword stores x 16 lines each,
// ~2x the MFMA cycles in address processing).
// ---------------------------------------------------------------------------
__global__ __launch_bounds__(256)
void dense_k(const ushort* __restrict__ xb, const ushort* __restrict__ t1,
             const ushort* __restrict__ t2, const ushort* __restrict__ wt,
             const float* __restrict__ bias, float* __restrict__ out) {
    __shared__ float lds[4][16 * 68];
    const int tid  = threadIdx.x;
    const int lane = tid & 63;
    const int wv   = tid >> 6;
    const int row0 = blockIdx.x * 64 + wv * 16;
    const int m    = lane & 15;
    const int quad = lane >> 4;
    int arow = row0 + m;
    if (arow >= NN) arow = NN - 1;          // clamp; stores are guarded

    f32x4 acc[4] = {};
    #pragma unroll
    for (int kb = 0; kb < 6; ++kb) {
        const int kbase = kb * 32;
        const ushort* seg = (kb < 2) ? xb : (kb < 4) ? t1 : t2;
        const int off = (kbase & 63) + quad * 8;
        bf16x8 a = *(const bf16x8*)(seg + (size_t)arow * F + off);
        #pragma unroll
        for (int t = 0; t < 4; ++t) {
            const int n = t * 16 + m;
            bf16x8 b = *(const bf16x8*)(wt + (size_t)n * 192 + kbase + quad * 8);
            acc[t] = __builtin_amdgcn_mfma_f32_16x16x32_bf16(a, b, acc[t], 0, 0, 0);
        }
    }

    float* sl = lds[wv];
    #pragma unroll
    for (int t = 0; t < 4; ++t) {
        const float bv = bias[t * 16 + m];
        #pragma unroll
        for (int rr = 0; rr < 4; ++rr)
            sl[(quad * 4 + rr) * 68 + t * 16 + m] = acc[t][rr] + bv;
    }
    __syncthreads();
    // read back row-major, store coalesced: pass p covers 4 rows x 256B
    const int m4 = (lane & 15) * 4;
    #pragma unroll
    for (int p = 0; p < 4; ++p) {
        const int rl = p * 4 + (lane >> 4);
        const int grow = row0 + rl;
        f32x4 v = *(const f32x4*)(sl + rl * 68 + m4);
        if (grow < NN)
            *(f32x4*)(out + (size_t)grow * F + m4) = v;
    }
}

extern "C" void kernel_launch(void* const* d_in, const int* in_sizes, int n_in,
                              void* d_out, int out_size, void* d_ws, size_t ws_size,
                              hipStream_t stream) {
    const float* x    = (const float*)d_in[0];
    const int*   rows = (const int*)  d_in[1];
    const int*   cols = (const int*)  d_in[2];
    const float* vals = (const float*)d_in[3];
    const float* w    = (const float*)d_in[4];  // [3][64][64] == [192][64]
    const float* bias = (const float*)d_in[5];  // [64]
    float* out = (float*)d_out;

    // Workspace (all fully rewritten every call; safe vs 0xAA poison):
    //   row_ptr (NN+1 int) | xb, t1b, t2b (N*64 bf16 each, 12.8MB) | wt (24KB)
    char* ws = (char*)d_ws;
    int* row_ptr = (int*)ws;
    size_t off = (((size_t)(NN + 1) * sizeof(int)) + 255) & ~(size_t)255;
    ushort* xb  = (ushort*)(ws + off);
    ushort* t1b = xb  + (size_t)NN * F;
    ushort* t2b = t1b + (size_t)NN * F;
    ushort* wt  = t2b + (size_t)NN * F;

    prep_k<<<B_CVT + B_RP + B_W, 256, 0, stream>>>(x, xb, rows, row_ptr, w, wt);
    spmm_k<false><<<NN / 32, 256, 0, stream>>>(row_ptr, cols, vals, xb,  nullptr, t1b);
    spmm_k<true ><<<NN / 32, 256, 0, stream>>>(row_ptr, cols, vals, t1b, xb,      t2b);
    dense_k<<<(NN + 63) / 64, 256, 0, stream>>>(xb, t1b, t2b, wt, bias, out);
}